// Round 1
// baseline (1928.794 us; speedup 1.0000x reference)
//
#include <hip/hip_runtime.h>

// LSTM_Critic: T=512, B=256, D_IN=64, H=128, two LSTMCell layers + 1-unit head.
// Persistent-kernel design: 16 workgroups x 512 threads; each wg owns 16 batch
// rows for the entire T loop (batch rows are independent -> no inter-wg sync).
// Weights converted to fp16 once (prep kernel) and held resident:
//   W_ih0, W_hh0, W_ih1 as MFMA B-fragments in VGPRs (loaded once),
//   W_hh1 in LDS [512][136] fp16 (pad 136 keeps ds_read_b128 16B-aligned and
//   limits bank conflicts to free 2-way).
// h0/h1 tiles double-buffered fp16 in LDS; c0/c1 fp32 in registers.
// MFMA: v_mfma_f32_16x16x32_f16, A[m=lane&15][k=quad*8+j], B[k][n=lane&15],
// C/D row=quad*4+reg, col=lane&15 (guide-verified layouts).

#define T_STEPS 512
#define BATCH   256
#define DIN     64
#define HDIM    128

typedef _Float16 half8 __attribute__((ext_vector_type(8)));
typedef float    f32x4 __attribute__((ext_vector_type(4)));

// ws layout (fp16 elements):
//   [0,      32768)  W_ih0 [512][64]
//   [32768,  98304)  W_hh0 [512][128]
//   [98304, 163840)  W_ih1 [512][128]
//   [163840,229376)  W_hh1 [512][128]
#define WS_IH0 0
#define WS_HH0 32768
#define WS_IH1 98304
#define WS_HH1 163840

__global__ void prep_convert(const float* __restrict__ wih0,
                             const float* __restrict__ whh0,
                             const float* __restrict__ wih1,
                             const float* __restrict__ whh1,
                             _Float16* __restrict__ ws) {
    int idx = blockIdx.x * 256 + threadIdx.x;           // 229376 total
    if (idx < 32768)       ws[idx] = (_Float16)wih0[idx];
    else if (idx < 98304)  ws[idx] = (_Float16)whh0[idx - 32768];
    else if (idx < 163840) ws[idx] = (_Float16)wih1[idx - 98304];
    else if (idx < 229376) ws[idx] = (_Float16)whh1[idx - 163840];
}

__device__ __forceinline__ float fast_sigmoid(float x) {
    return __builtin_amdgcn_rcpf(1.0f + __expf(-x));
}
__device__ __forceinline__ float fast_tanh(float x) {
    // 1 - 2/(1+exp(2x)): saturates correctly at +-1 (rcp(inf)=0)
    return 1.0f - 2.0f * __builtin_amdgcn_rcpf(1.0f + __expf(2.0f * x));
}

// LDS layout (bytes):
//   0      : W_hh1 [512][136] fp16            = 139264
//   139264 : h0buf [2][16][136] fp16          =   8704
//   147968 : h1buf [2][16][136] fp16          =   8704
//   156672 : vpart [8][16] f32                =    512
//   total 157184  (<= 160 KiB LDS/CU; forces 1 wg/CU)
#define LDS_WHH1  0
#define LDS_H0    139264
#define LDS_H1    147968
#define LDS_VPART 156672
#define LDS_BYTES 157184
#define HROW 136      // padded fp16 row stride for h tiles and W_hh1
#define HTILE (16*HROW)

__global__ __launch_bounds__(512, 2) void lstm_persistent(
        const float* __restrict__ state, const _Float16* __restrict__ wsw,
        const float* __restrict__ b_ih0, const float* __restrict__ b_hh0,
        const float* __restrict__ b_ih1, const float* __restrict__ b_hh1,
        const float* __restrict__ w_out, const float* __restrict__ b_out,
        float* __restrict__ out) {
    extern __shared__ char smem[];
    _Float16* whh1 = (_Float16*)(smem + LDS_WHH1);
    _Float16* h0b  = (_Float16*)(smem + LDS_H0);
    _Float16* h1b  = (_Float16*)(smem + LDS_H1);
    float*    vpart = (float*)(smem + LDS_VPART);

    const int tid  = threadIdx.x;
    const int w    = tid >> 6;        // wave 0..7 -> owns u in [16w,16w+16)
    const int lane = tid & 63;
    const int col  = lane & 15;       // MFMA m/n index
    const int quad = lane >> 4;       // 0..3
    const int rowbase = blockIdx.x * 16;

    // ---- one-time: W_hh1 global fp16 -> padded LDS ----
    const _Float16* whh1g = wsw + WS_HH1;
    #pragma unroll
    for (int it = 0; it < 16; ++it) {
        int flat = (it * 512 + tid) * 8;        // 8 fp16 per thread per iter
        int r = flat >> 7, c = flat & 127;
        *(half8*)(whh1 + r * HROW + c) = *(const half8*)(whh1g + flat);
    }
    // zero both h buffers (t=0 reads buf 0; buf 1 harmless)
    for (int i = tid; i < 2 * HTILE; i += 512) {
        h0b[i] = (_Float16)0.0f;
        h1b[i] = (_Float16)0.0f;
    }

    // ---- one-time: resident B-fragments in VGPRs ----
    // B[k][n]: n = j (weight row) = nt*128 + w*16 + col; k = kt*32 + quad*8 + jj
    half8 wih0f[4][2], whh0f[4][4], wih1f[4][4];
    float bias0[4], bias1[4];
    #pragma unroll
    for (int nt = 0; nt < 4; ++nt) {
        int j = nt * 128 + w * 16 + col;
        #pragma unroll
        for (int kt = 0; kt < 2; ++kt)
            wih0f[nt][kt] = *(const half8*)(wsw + WS_IH0 + j * 64 + kt * 32 + quad * 8);
        #pragma unroll
        for (int kt = 0; kt < 4; ++kt) {
            whh0f[nt][kt] = *(const half8*)(wsw + WS_HH0 + j * 128 + kt * 32 + quad * 8);
            wih1f[nt][kt] = *(const half8*)(wsw + WS_IH1 + j * 128 + kt * 32 + quad * 8);
        }
        bias0[nt] = b_ih0[j] + b_hh0[j];
        bias1[nt] = b_ih1[j] + b_hh1[j];
    }
    const float woutv = w_out[w * 16 + col];   // head weight for this lane's u
    const float bout  = b_out[0];
    float c0[4] = {0.f, 0.f, 0.f, 0.f};
    float c1[4] = {0.f, 0.f, 0.f, 0.f};

    __syncthreads();

    // per-lane x pointer: row = rowbase+col (A m-index), k base = quad*8
    const float* xlane = state + (size_t)(rowbase + col) * DIN + quad * 8;

    #pragma unroll 1
    for (int t = 0; t < T_STEPS; ++t) {
        const int pb = t & 1;        // read buffer (prev h)
        const int cb = pb ^ 1;       // write buffer (cur h)

        // ================= Layer 0 =================
        // A-frags: x_t from global (fp32 -> fp16), h0_prev from LDS
        half8 ax[2];
        {
            const float* p = xlane + (size_t)t * (BATCH * DIN);
            #pragma unroll
            for (int kt = 0; kt < 2; ++kt) {
                f32x4 f0 = *(const f32x4*)(p + kt * 32);
                f32x4 f1 = *(const f32x4*)(p + kt * 32 + 4);
                half8 h;
                h[0]=(_Float16)f0[0]; h[1]=(_Float16)f0[1];
                h[2]=(_Float16)f0[2]; h[3]=(_Float16)f0[3];
                h[4]=(_Float16)f1[0]; h[5]=(_Float16)f1[1];
                h[6]=(_Float16)f1[2]; h[7]=(_Float16)f1[3];
                ax[kt] = h;
            }
        }
        half8 ah[4];
        #pragma unroll
        for (int kt = 0; kt < 4; ++kt)
            ah[kt] = *(const half8*)(h0b + pb * HTILE + col * HROW + kt * 32 + quad * 8);

        f32x4 acc[4];
        #pragma unroll
        for (int nt = 0; nt < 4; ++nt) {
            f32x4 a = {bias0[nt], bias0[nt], bias0[nt], bias0[nt]};
            acc[nt] = a;
        }
        #pragma unroll
        for (int kt = 0; kt < 2; ++kt)
            #pragma unroll
            for (int nt = 0; nt < 4; ++nt)
                acc[nt] = __builtin_amdgcn_mfma_f32_16x16x32_f16(ax[kt], wih0f[nt][kt], acc[nt], 0, 0, 0);
        #pragma unroll
        for (int kt = 0; kt < 4; ++kt)
            #pragma unroll
            for (int nt = 0; nt < 4; ++nt)
                acc[nt] = __builtin_amdgcn_mfma_f32_16x16x32_f16(ah[kt], whh0f[nt][kt], acc[nt], 0, 0, 0);

        // activations: lane owns (r = quad*4+i, u = w*16+col); c0 stays in VGPRs
        #pragma unroll
        for (int i = 0; i < 4; ++i) {
            float ig = fast_sigmoid(acc[0][i]);
            float fg = fast_sigmoid(acc[1][i]);
            float gg = fast_tanh(acc[2][i]);
            float og = fast_sigmoid(acc[3][i]);
            float c  = fg * c0[i] + ig * gg;
            c0[i] = c;
            float h0v = og * fast_tanh(c);
            h0b[cb * HTILE + (quad * 4 + i) * HROW + (w * 16 + col)] = (_Float16)h0v;
        }
        __syncthreads();   // h0_cur complete before layer-1 A-frag reads

        // ================= Layer 1 =================
        #pragma unroll
        for (int nt = 0; nt < 4; ++nt) {
            f32x4 a = {bias1[nt], bias1[nt], bias1[nt], bias1[nt]};
            acc[nt] = a;
        }
        // input part: h0_cur (LDS) x W_ih1 (VGPR-resident)
        #pragma unroll
        for (int kt = 0; kt < 4; ++kt) {
            half8 a0 = *(const half8*)(h0b + cb * HTILE + col * HROW + kt * 32 + quad * 8);
            #pragma unroll
            for (int nt = 0; nt < 4; ++nt)
                acc[nt] = __builtin_amdgcn_mfma_f32_16x16x32_f16(a0, wih1f[nt][kt], acc[nt], 0, 0, 0);
        }
        // recurrent part: h1_prev (LDS) x W_hh1 (LDS-resident B-frags)
        #pragma unroll
        for (int kt = 0; kt < 4; ++kt) {
            half8 a1 = *(const half8*)(h1b + pb * HTILE + col * HROW + kt * 32 + quad * 8);
            #pragma unroll
            for (int nt = 0; nt < 4; ++nt) {
                int j = nt * 128 + w * 16 + col;
                half8 bfr = *(const half8*)(whh1 + j * HROW + kt * 32 + quad * 8);
                acc[nt] = __builtin_amdgcn_mfma_f32_16x16x32_f16(a1, bfr, acc[nt], 0, 0, 0);
            }
        }
        float h1v[4];
        #pragma unroll
        for (int i = 0; i < 4; ++i) {
            float ig = fast_sigmoid(acc[0][i]);
            float fg = fast_sigmoid(acc[1][i]);
            float gg = fast_tanh(acc[2][i]);
            float og = fast_sigmoid(acc[3][i]);
            float c  = fg * c1[i] + ig * gg;
            c1[i] = c;
            h1v[i] = og * fast_tanh(c);
            h1b[cb * HTILE + (quad * 4 + i) * HROW + (w * 16 + col)] = (_Float16)h1v[i];
        }

        // value head partials in-register: reduce over the 16 u-lanes of this wave
        #pragma unroll
        for (int i = 0; i < 4; ++i) {
            float pr = h1v[i] * woutv;
            pr += __shfl_xor(pr, 1);
            pr += __shfl_xor(pr, 2);
            pr += __shfl_xor(pr, 4);
            pr += __shfl_xor(pr, 8);
            if (col == 0) vpart[w * 16 + quad * 4 + i] = pr;
        }
        __syncthreads();   // h1_cur + vpart complete

        // cross-wave combine + store v[t, rows]
        if (tid < 16) {
            float s = bout;
            #pragma unroll
            for (int wv = 0; wv < 8; ++wv) s += vpart[wv * 16 + tid];
            out[t * BATCH + rowbase + tid] = s;
        }
    }
}

extern "C" void kernel_launch(void* const* d_in, const int* in_sizes, int n_in,
                              void* d_out, int out_size, void* d_ws, size_t ws_size,
                              hipStream_t stream) {
    const float* state = (const float*)d_in[0];
    const float* wih0  = (const float*)d_in[1];
    const float* whh0  = (const float*)d_in[2];
    const float* bih0  = (const float*)d_in[3];
    const float* bhh0  = (const float*)d_in[4];
    const float* wih1  = (const float*)d_in[5];
    const float* whh1  = (const float*)d_in[6];
    const float* bih1  = (const float*)d_in[7];
    const float* bhh1  = (const float*)d_in[8];
    const float* wout  = (const float*)d_in[9];
    const float* bout  = (const float*)d_in[10];
    _Float16* wsh = (_Float16*)d_ws;

    // fp32 -> fp16 weight conversion (229376 elements)
    prep_convert<<<896, 256, 0, stream>>>(wih0, whh0, wih1, whh1, wsh);
    // persistent recurrence: 16 wgs x 512 threads, 157184 B dynamic LDS
    lstm_persistent<<<16, 512, LDS_BYTES, stream>>>(
        state, wsh, bih0, bhh0, bih1, bhh1, wout, bout, (float*)d_out);
}

// Round 2
// 1265.629 us; speedup vs baseline: 1.5240x; 1.5240x over previous
//
#include <hip/hip_runtime.h>

// LSTM_Critic: T=512, B=256, D_IN=64, H=128. Persistent kernel: 16 WGs x 512
// threads, each WG owns 16 batch rows for all T steps. Round-2 design:
//  - whh0/wih1 B-frags pinned resident in AGPRs (128 regs) via asm "+a".
//  - wih0 streamed from L2 each step (8 b128/thread), whh1 in LDS.
//  - XOR chunk-swizzled LDS (stride 128, chunk^row) -> conflict-free b128.
//  - ONE barrier per step (double-buffered h0/h1; hazards verified).
//  - x state pre-converted to fp16 in ws (fallback fp32), prefetched 1 step.
//  - value head = extra MFMA vs wout on wave 7 (computes step t-1), no shuffles.

#define T_STEPS 512
#define BATCH   256
#define DIN     64
#define HDIM    128

typedef _Float16 half8 __attribute__((ext_vector_type(8)));
typedef float    f32x4 __attribute__((ext_vector_type(4)));

// ws layout (fp16 element offsets)
#define WS_IH0 0          // [512][64]
#define WS_HH0 32768      // [512][128]
#define WS_IH1 98304      // [512][128]
#define WS_HH1 163840     // [512][128]
#define WS_X   229376     // [512][256][64] fp16 state (XH path)
#define WS_X_ELEMS (T_STEPS * BATCH * DIN)
#define WS_NEED ((size_t)(WS_X + WS_X_ELEMS) * 2)

__global__ void prep_weights(const float* __restrict__ wih0,
                             const float* __restrict__ whh0,
                             const float* __restrict__ wih1,
                             const float* __restrict__ whh1,
                             _Float16* __restrict__ ws) {
    int idx = blockIdx.x * 256 + threadIdx.x;           // 229376 total
    if (idx < 32768)       ws[idx] = (_Float16)wih0[idx];
    else if (idx < 98304)  ws[idx] = (_Float16)whh0[idx - 32768];
    else if (idx < 163840) ws[idx] = (_Float16)wih1[idx - 98304];
    else if (idx < 229376) ws[idx] = (_Float16)whh1[idx - 163840];
}

__global__ void prep_state(const float* __restrict__ s, _Float16* __restrict__ d) {
    int i = (blockIdx.x * 256 + threadIdx.x) * 8;       // 8388608 elements
    f32x4 a = *(const f32x4*)(s + i);
    f32x4 b = *(const f32x4*)(s + i + 4);
    half8 h;
    h[0]=(_Float16)a[0]; h[1]=(_Float16)a[1]; h[2]=(_Float16)a[2]; h[3]=(_Float16)a[3];
    h[4]=(_Float16)b[0]; h[5]=(_Float16)b[1]; h[6]=(_Float16)b[2]; h[7]=(_Float16)b[3];
    *(half8*)(d + i) = h;
}

__device__ __forceinline__ float fast_sigmoid(float x) {
    return __builtin_amdgcn_rcpf(1.0f + __expf(-x));
}
__device__ __forceinline__ float fast_tanh(float x) {
    return 1.0f - 2.0f * __builtin_amdgcn_rcpf(1.0f + __expf(2.0f * x));
}

// LDS (fp16 element offsets). Swizzle: element (row,k) of a [R][128] tile at
//   row*128 + (((k>>3) ^ (row&15))*8) + (k&7)
#define L_WHH1 0          // 512x128            = 65536
#define L_H0   65536      // 2 x 16x128         =  4096
#define L_H1   69632      // 2 x 16x128         =  4096
#define L_WOUT 73728      // 128                =   128
#define LDS_BYTES ((73728 + 128) * 2)   // 147712 B

template<bool XH>
__global__ __launch_bounds__(512, 2) void lstm_persistent(
        const float* __restrict__ state32, const _Float16* __restrict__ wsw,
        const float* __restrict__ b_ih0, const float* __restrict__ b_hh0,
        const float* __restrict__ b_ih1, const float* __restrict__ b_hh1,
        const float* __restrict__ w_out, const float* __restrict__ b_out,
        float* __restrict__ out) {
    extern __shared__ _Float16 lds[];
    _Float16* whh1  = lds + L_WHH1;
    _Float16* h0b   = lds + L_H0;
    _Float16* h1b   = lds + L_H1;
    _Float16* woutl = lds + L_WOUT;

    const int tid  = threadIdx.x;
    const int w    = tid >> 6;         // wave 0..7: owns gate-rows nt*128 + [16w,16w+16)
    const int lane = tid & 63;
    const int col  = lane & 15;        // MFMA m/n index
    const int quad = lane >> 4;        // 0..3
    const int rowbase = blockIdx.x * 16;
    const int j0 = w * 16 + col;       // weight-row within each 128-gate chunk

    // ---- one-time: whh1 -> LDS (chunk-swizzled) ----
    const _Float16* whh1g = wsw + WS_HH1;
    #pragma unroll
    for (int it = 0; it < 16; ++it) {
        int flat = (it * 512 + tid) * 8;
        int r = flat >> 7;
        int chunk = (flat >> 3) & 15;
        *(half8*)(whh1 + r * 128 + ((chunk ^ (r & 15)) * 8)) = *(const half8*)(whh1g + flat);
    }
    // zero h0b+h1b (contiguous 8192 fp16)
    {
        half8 z;
        #pragma unroll
        for (int jj = 0; jj < 8; ++jj) z[jj] = (_Float16)0.0f;
        for (int i = tid * 8; i < 8192; i += 4096) *(half8*)(h0b + i) = z;
    }
    if (tid < 128) woutl[tid] = (_Float16)w_out[tid];

    // ---- resident B-frags (pinned to AGPRs) ----
    half8 whh0f[4][4], wih1f[4][4];
    float bias0[4], bias1[4];
    #pragma unroll
    for (int nt = 0; nt < 4; ++nt) {
        int j = nt * 128 + j0;
        #pragma unroll
        for (int kt = 0; kt < 4; ++kt) {
            whh0f[nt][kt] = *(const half8*)(wsw + WS_HH0 + j * 128 + kt * 32 + quad * 8);
            wih1f[nt][kt] = *(const half8*)(wsw + WS_IH1 + j * 128 + kt * 32 + quad * 8);
        }
        bias0[nt] = b_ih0[j] + b_hh0[j];
        bias1[nt] = b_ih1[j] + b_hh1[j];
    }
    #pragma unroll
    for (int nt = 0; nt < 4; ++nt)
        #pragma unroll
        for (int kt = 0; kt < 4; ++kt) {
            asm volatile("" : "+a"(whh0f[nt][kt]));
            asm volatile("" : "+a"(wih1f[nt][kt]));
        }
    const float bout = b_out[0];

    // addressing precompute (fp16 element offsets)
    int swz[4], hoff[4];
    #pragma unroll
    for (int kt = 0; kt < 4; ++kt) {
        swz[kt]  = ((kt * 4 + quad) ^ col) * 8;
        hoff[kt] = col * 128 + swz[kt];
    }
    int w0off[4];
    #pragma unroll
    for (int i = 0; i < 4; ++i) {
        int row = quad * 4 + i;
        w0off[i] = row * 128 + (((2 * w + (col >> 3)) ^ row) * 8) + (col & 7);
    }

    float c0[4] = {0.f,0.f,0.f,0.f}, c1[4] = {0.f,0.f,0.f,0.f};

    // x pointers + first prefetch
    const _Float16* xph = wsw + WS_X + (size_t)(rowbase + col) * DIN + quad * 8;
    const float*    xpf = state32 + (size_t)(rowbase + col) * DIN + quad * 8;
    half8 nxh0, nxh1;
    f32x4 nxf0, nxf1, nxf2, nxf3;
    if constexpr (XH) {
        nxh0 = *(const half8*)(xph);
        nxh1 = *(const half8*)(xph + 32);
    } else {
        nxf0 = *(const f32x4*)(xpf);      nxf1 = *(const f32x4*)(xpf + 4);
        nxf2 = *(const f32x4*)(xpf + 32); nxf3 = *(const f32x4*)(xpf + 36);
    }

    __syncthreads();   // LDS init complete

    const _Float16* wih0g = wsw + WS_IH0;

    #pragma unroll 1
    for (int t = 0; t < T_STEPS; ++t) {
        const int pbo = (t & 1) * 2048;        // prev h buffer (element off)
        const int cbo = pbo ^ 2048;            // cur  h buffer

        // current x frags (from prefetch issued last iteration)
        half8 ax0, ax1;
        if constexpr (XH) { ax0 = nxh0; ax1 = nxh1; }
        else {
            #pragma unroll
            for (int jj = 0; jj < 4; ++jj) {
                ax0[jj]   = (_Float16)nxf0[jj]; ax0[jj+4] = (_Float16)nxf1[jj];
                ax1[jj]   = (_Float16)nxf2[jj]; ax1[jj+4] = (_Float16)nxf3[jj];
            }
        }

        // ---- Layer 0 ----
        // streamed wih0 B-frags (L2-resident; MFMAs using them come last)
        half8 wif[4][2];
        #pragma unroll
        for (int nt = 0; nt < 4; ++nt)
            #pragma unroll
            for (int kt = 0; kt < 2; ++kt)
                wif[nt][kt] = *(const half8*)(wih0g + (nt * 128 + j0) * 64 + kt * 32 + quad * 8);

        half8 ah[4];
        #pragma unroll
        for (int kt = 0; kt < 4; ++kt)
            ah[kt] = *(const half8*)(h0b + pbo + hoff[kt]);

        f32x4 acc[4];
        #pragma unroll
        for (int nt = 0; nt < 4; ++nt) {
            f32x4 b = {bias0[nt], bias0[nt], bias0[nt], bias0[nt]};
            acc[nt] = b;
        }
        #pragma unroll
        for (int kt = 0; kt < 4; ++kt)
            #pragma unroll
            for (int nt = 0; nt < 4; ++nt)
                acc[nt] = __builtin_amdgcn_mfma_f32_16x16x32_f16(ah[kt], whh0f[nt][kt], acc[nt], 0, 0, 0);
        #pragma unroll
        for (int kt = 0; kt < 2; ++kt) {
            half8 axk = kt ? ax1 : ax0;
            #pragma unroll
            for (int nt = 0; nt < 4; ++nt)
                acc[nt] = __builtin_amdgcn_mfma_f32_16x16x32_f16(axk, wif[nt][kt], acc[nt], 0, 0, 0);
        }

        // prefetch x(t+1): issued here, consumed at top of next iteration
        {
            int tn = (t + 1 < T_STEPS) ? t + 1 : t;
            if constexpr (XH) {
                const _Float16* xq = xph + (size_t)tn * (BATCH * DIN);
                nxh0 = *(const half8*)(xq);
                nxh1 = *(const half8*)(xq + 32);
            } else {
                const float* xq = xpf + (size_t)tn * (BATCH * DIN);
                nxf0 = *(const f32x4*)(xq);      nxf1 = *(const f32x4*)(xq + 4);
                nxf2 = *(const f32x4*)(xq + 32); nxf3 = *(const f32x4*)(xq + 36);
            }
        }

        // L0 activations; c0 in regs; write h0(t)
        #pragma unroll
        for (int i = 0; i < 4; ++i) {
            float ig = fast_sigmoid(acc[0][i]);
            float fg = fast_sigmoid(acc[1][i]);
            float gg = fast_tanh(acc[2][i]);
            float og = fast_sigmoid(acc[3][i]);
            float c  = fg * c0[i] + ig * gg;
            c0[i] = c;
            h0b[cbo + w0off[i]] = (_Float16)(og * fast_tanh(c));
        }

        __syncthreads();   // the ONLY barrier per step

        // ---- Layer 1 ----
        #pragma unroll
        for (int nt = 0; nt < 4; ++nt) {
            f32x4 b = {bias1[nt], bias1[nt], bias1[nt], bias1[nt]};
            acc[nt] = b;
        }
        #pragma unroll
        for (int kt = 0; kt < 4; ++kt) {
            half8 a0 = *(const half8*)(h0b + cbo + hoff[kt]);   // h0(t)
            half8 a1 = *(const half8*)(h1b + pbo + hoff[kt]);   // h1(t-1)
            #pragma unroll
            for (int nt = 0; nt < 4; ++nt)
                acc[nt] = __builtin_amdgcn_mfma_f32_16x16x32_f16(a0, wih1f[nt][kt], acc[nt], 0, 0, 0);
            #pragma unroll
            for (int nt = 0; nt < 4; ++nt) {
                half8 bfr = *(const half8*)(whh1 + nt * 16384 + j0 * 128 + swz[kt]);
                acc[nt] = __builtin_amdgcn_mfma_f32_16x16x32_f16(a1, bfr, acc[nt], 0, 0, 0);
            }
        }
        #pragma unroll
        for (int i = 0; i < 4; ++i) {
            float ig = fast_sigmoid(acc[0][i]);
            float fg = fast_sigmoid(acc[1][i]);
            float gg = fast_tanh(acc[2][i]);
            float og = fast_sigmoid(acc[3][i]);
            float c  = fg * c1[i] + ig * gg;
            c1[i] = c;
            h1b[cbo + w0off[i]] = (_Float16)(og * fast_tanh(c));
        }

        // value head for step t-1 on wave 7: v = h1(t-1) @ wout
        if (w == 7) {
            f32x4 vh = {0.f, 0.f, 0.f, 0.f};
            #pragma unroll
            for (int kt = 0; kt < 4; ++kt) {
                half8 a1 = *(const half8*)(h1b + pbo + hoff[kt]);  // safe re-read (see hazard note)
                half8 bw = *(const half8*)(woutl + kt * 32 + quad * 8);
                if (col != 0) {
                    #pragma unroll
                    for (int jj = 0; jj < 8; ++jj) bw[jj] = (_Float16)0.0f;
                }
                vh = __builtin_amdgcn_mfma_f32_16x16x32_f16(a1, bw, vh, 0, 0, 0);
            }
            if (t > 0 && col == 0) {
                f32x4 vo = {vh[0] + bout, vh[1] + bout, vh[2] + bout, vh[3] + bout};
                *(f32x4*)(out + (size_t)(t - 1) * BATCH + rowbase + quad * 4) = vo;
            }
        }
    }

    // tail: head for t = T-1 (h1(T-1) lives in buffer ((T-1)&1)^1)
    __syncthreads();
    if (w == 7) {
        const int fbo = (((T_STEPS - 1) & 1) ^ 1) * 2048;
        f32x4 vh = {0.f, 0.f, 0.f, 0.f};
        #pragma unroll
        for (int kt = 0; kt < 4; ++kt) {
            half8 a1 = *(const half8*)(h1b + fbo + hoff[kt]);
            half8 bw = *(const half8*)(woutl + kt * 32 + quad * 8);
            if (col != 0) {
                #pragma unroll
                for (int jj = 0; jj < 8; ++jj) bw[jj] = (_Float16)0.0f;
            }
            vh = __builtin_amdgcn_mfma_f32_16x16x32_f16(a1, bw, vh, 0, 0, 0);
        }
        if (col == 0) {
            f32x4 vo = {vh[0] + bout, vh[1] + bout, vh[2] + bout, vh[3] + bout};
            *(f32x4*)(out + (size_t)(T_STEPS - 1) * BATCH + rowbase + quad * 4) = vo;
        }
    }
}

extern "C" void kernel_launch(void* const* d_in, const int* in_sizes, int n_in,
                              void* d_out, int out_size, void* d_ws, size_t ws_size,
                              hipStream_t stream) {
    const float* state = (const float*)d_in[0];
    const float* wih0  = (const float*)d_in[1];
    const float* whh0  = (const float*)d_in[2];
    const float* bih0  = (const float*)d_in[3];
    const float* bhh0  = (const float*)d_in[4];
    const float* wih1  = (const float*)d_in[5];
    const float* whh1  = (const float*)d_in[6];
    const float* bih1  = (const float*)d_in[7];
    const float* bhh1  = (const float*)d_in[8];
    const float* wout  = (const float*)d_in[9];
    const float* bout  = (const float*)d_in[10];
    _Float16* wsh = (_Float16*)d_ws;

    prep_weights<<<896, 256, 0, stream>>>(wih0, whh0, wih1, whh1, wsh);

    const bool xh = ws_size >= WS_NEED;
    if (xh) {
        prep_state<<<WS_X_ELEMS / (256 * 8), 256, 0, stream>>>(state, wsh + WS_X);
        lstm_persistent<true><<<16, 512, LDS_BYTES, stream>>>(
            state, wsh, bih0, bhh0, bih1, bhh1, wout, bout, (float*)d_out);
    } else {
        lstm_persistent<false><<<16, 512, LDS_BYTES, stream>>>(
            state, wsh, bih0, bhh0, bih1, bhh1, wout, bout, (float*)d_out);
    }
}

// Round 3
// 1022.070 us; speedup vs baseline: 1.8871x; 1.2383x over previous
//
#include <hip/hip_runtime.h>

// LSTM_Critic: T=512, B=256, D_IN=64, H=128. Round-3: layer-pipelined
// persistent kernel, ONE dispatch of 32 WGs x 512 threads:
//   blocks 0..15  (producers): layer-0 LSTM for batch-tile b, write h0(t) to a
//                  full-depth FIFO in ws (one slot per t -> deadlock-free).
//   blocks 16..31 (consumers): layer-1 LSTM + value head, poll per-(tile,t)
//                  flags with agent-scope acquire; producers publish with
//                  agent-scope release (handles cross-XCD L2 non-coherence).
// Weights pre-scaled by log2e / 2*log2e in prep so activations are pure
// exp2/rcp (no per-activation mul). Recurrent weights in swizzled LDS
// (R2-verified conflict-free); input-side weights resident in VGPRs.
// Fallbacks for smaller ws: pipelined w/ fp32 x; R2 monolithic kernel.

#define T_STEPS 512
#define BATCH   256
#define DIN     64

typedef _Float16 half8 __attribute__((ext_vector_type(8)));
typedef float    f32x4 __attribute__((ext_vector_type(4)));

#define LOG2E  1.44269504088896f
#define LOG2E2 2.88539008177793f

// ---- ws layout (element offsets in fp16 halfs unless noted) ----
#define WH_IH0 0          // [512][64]
#define WH_HH0 32768      // [512][128]
#define WH_IH1 98304      // [512][128]
#define WH_HH1 163840     // [512][128]
#define WH_END 229376
// mode 2: + fp16 x + slab + flags
#define WH_X2     229376                   // 8388608 halfs
#define WH_SLAB2  8617984                  // 16777216 halfs
#define WB_FLAG2  50790400                 // byte offset, 8192 ints
#define WS2_TOTAL 50823168
// mode 1: + slab + flags (x stays fp32 from input)
#define WH_SLAB1  229376
#define WB_FLAG1  34013184
#define WS1_TOTAL 34045952
// mode 0 (monolithic): optional fp16 x at WH_X2
#define WS0XH_TOTAL ((size_t)(WH_X2 + 8388608) * 2)

__global__ void prep_weights(const float* __restrict__ wih0,
                             const float* __restrict__ whh0,
                             const float* __restrict__ wih1,
                             const float* __restrict__ whh1,
                             _Float16* __restrict__ ws) {
    int idx = blockIdx.x * 256 + threadIdx.x;   // 229376 total
    float v; int row;
    if (idx < 32768)       { row = idx >> 6;             v = wih0[idx]; }
    else if (idx < 98304)  { row = (idx - 32768) >> 7;   v = whh0[idx - 32768]; }
    else if (idx < 163840) { row = (idx - 98304) >> 7;   v = wih1[idx - 98304]; }
    else                   { row = (idx - 163840) >> 7;  v = whh1[idx - 163840]; }
    // gate chunk 2 (g) uses tanh -> scale 2*log2e; others sigmoid -> log2e
    float sc = ((row >> 7) == 2) ? LOG2E2 : LOG2E;
    ws[idx] = (_Float16)(v * sc);
}

__global__ void prep_state(const float* __restrict__ s, _Float16* __restrict__ d) {
    int i = (blockIdx.x * 256 + threadIdx.x) * 8;   // 8388608 elements
    f32x4 a = *(const f32x4*)(s + i);
    f32x4 b = *(const f32x4*)(s + i + 4);
    half8 h;
    h[0]=(_Float16)a[0]; h[1]=(_Float16)a[1]; h[2]=(_Float16)a[2]; h[3]=(_Float16)a[3];
    h[4]=(_Float16)b[0]; h[5]=(_Float16)b[1]; h[6]=(_Float16)b[2]; h[7]=(_Float16)b[3];
    *(half8*)(d + i) = h;
}

// activations on pre-scaled gate values
__device__ __forceinline__ float sig2(float y) {        // y = x*log2e
    return __builtin_amdgcn_rcpf(1.0f + __builtin_amdgcn_exp2f(-y));
}
__device__ __forceinline__ float tanh2(float y2) {      // y2 = x*2*log2e
    return 1.0f - 2.0f * __builtin_amdgcn_rcpf(1.0f + __builtin_amdgcn_exp2f(y2));
}
__device__ __forceinline__ float tanh_c(float c) {      // c unscaled
    return 1.0f - 2.0f * __builtin_amdgcn_rcpf(1.0f + __builtin_amdgcn_exp2f(c * LOG2E2));
}

// =====================  pipelined kernel  =====================
// LDS (halfs): wrec[512][128] swizzled = 65536 | hdb[2][16][128] = 4096 | woutl[128]
#define PIPE_LDS_BYTES ((65536 + 4096 + 128) * 2)

template<bool XH>
__global__ __launch_bounds__(512, 2) void lstm_pipe(
        const float* __restrict__ state32, const _Float16* __restrict__ wsw,
        const float* __restrict__ b_ih0, const float* __restrict__ b_hh0,
        const float* __restrict__ b_ih1, const float* __restrict__ b_hh1,
        const float* __restrict__ w_out, const float* __restrict__ b_out,
        _Float16* __restrict__ slab, int* __restrict__ flags,
        const _Float16* __restrict__ xh, float* __restrict__ out) {
    extern __shared__ _Float16 lds[];
    _Float16* wrec  = lds;            // recurrent weights (whh0 / whh1), swizzled
    _Float16* hdb   = lds + 65536;    // h double-buffer [2][16][128], swizzled
    _Float16* woutl = lds + 69632;    // head weights (consumer)

    const int tid  = threadIdx.x;
    const int w    = tid >> 6;
    const int lane = tid & 63;
    const int col  = lane & 15;
    const int quad = lane >> 4;
    const bool producer = blockIdx.x < 16;
    const int tile = blockIdx.x & 15;
    const int rowbase = tile * 16;
    const int j0 = w * 16 + col;

    // ---- one-time LDS init ----
    const _Float16* wrg = wsw + (producer ? WH_HH0 : WH_HH1);
    #pragma unroll
    for (int it = 0; it < 16; ++it) {
        int flat = (it * 512 + tid) * 8;
        int r = flat >> 7, chunk = (flat >> 3) & 15;
        *(half8*)(wrec + r * 128 + ((chunk ^ (r & 15)) * 8)) = *(const half8*)(wrg + flat);
    }
    {
        half8 z;
        #pragma unroll
        for (int jj = 0; jj < 8; ++jj) z[jj] = (_Float16)0.0f;
        *(half8*)(hdb + tid * 8) = z;   // 512*8 = 4096 halfs
    }
    if (!producer && tid < 128) woutl[tid] = (_Float16)w_out[tid];

    // ---- resident input-side B-frags + scaled biases ----
    half8 wresf[4][4];   // producer uses [nt][0..1] (wih0), consumer [nt][0..3] (wih1)
    float bias[4];
    #pragma unroll
    for (int nt = 0; nt < 4; ++nt) {
        int j = nt * 128 + j0;
        float sc = (nt == 2) ? LOG2E2 : LOG2E;
        if (producer) {
            #pragma unroll
            for (int kt = 0; kt < 2; ++kt)
                wresf[nt][kt] = *(const half8*)(wsw + WH_IH0 + j * 64 + kt * 32 + quad * 8);
            bias[nt] = (b_ih0[j] + b_hh0[j]) * sc;
        } else {
            #pragma unroll
            for (int kt = 0; kt < 4; ++kt)
                wresf[nt][kt] = *(const half8*)(wsw + WH_IH1 + j * 128 + kt * 32 + quad * 8);
            bias[nt] = (b_ih1[j] + b_hh1[j]) * sc;
        }
    }
    const float bout = b_out[0];

    // swizzled-address precompute (R2-verified, 0 bank conflicts)
    int swz[4], hoff[4], w0off[4];
    #pragma unroll
    for (int kt = 0; kt < 4; ++kt) {
        swz[kt]  = ((kt * 4 + quad) ^ col) * 8;
        hoff[kt] = col * 128 + swz[kt];
    }
    #pragma unroll
    for (int i = 0; i < 4; ++i) {
        int row = quad * 4 + i;
        w0off[i] = row * 128 + (((2 * w + (col >> 3)) ^ row) * 8) + (col & 7);
    }
    float cc[4] = {0.f, 0.f, 0.f, 0.f};

    __syncthreads();

    if (producer) {
        // ================= layer-0 producer =================
        const _Float16* xph = xh + (size_t)(rowbase + col) * DIN + quad * 8;
        const float*    xpf = state32 + (size_t)(rowbase + col) * DIN + quad * 8;
        half8 nxh0, nxh1;
        f32x4 nxf0, nxf1, nxf2, nxf3;
        if constexpr (XH) {
            nxh0 = *(const half8*)(xph);
            nxh1 = *(const half8*)(xph + 32);
        } else {
            nxf0 = *(const f32x4*)(xpf);      nxf1 = *(const f32x4*)(xpf + 4);
            nxf2 = *(const f32x4*)(xpf + 32); nxf3 = *(const f32x4*)(xpf + 36);
        }

        #pragma unroll 1
        for (int t = 0; t < T_STEPS; ++t) {
            const int pbo = (t & 1) * 2048, cbo = pbo ^ 2048;
            __syncthreads();   // t-1 LDS writes visible; vmcnt drained (slab stores done)
            if (t > 0 && tid == 0)
                __hip_atomic_store(flags + (t - 1) * 16 + tile, t,
                                   __ATOMIC_RELEASE, __HIP_MEMORY_SCOPE_AGENT);

            half8 ax0, ax1;
            if constexpr (XH) { ax0 = nxh0; ax1 = nxh1; }
            else {
                #pragma unroll
                for (int jj = 0; jj < 4; ++jj) {
                    ax0[jj]   = (_Float16)nxf0[jj]; ax0[jj+4] = (_Float16)nxf1[jj];
                    ax1[jj]   = (_Float16)nxf2[jj]; ax1[jj+4] = (_Float16)nxf3[jj];
                }
            }
            half8 ah[4];
            #pragma unroll
            for (int kt = 0; kt < 4; ++kt)
                ah[kt] = *(const half8*)(hdb + pbo + hoff[kt]);

            f32x4 acc[4];
            #pragma unroll
            for (int nt = 0; nt < 4; ++nt) {
                f32x4 b = {bias[nt], bias[nt], bias[nt], bias[nt]};
                acc[nt] = b;
            }
            #pragma unroll
            for (int kt = 0; kt < 4; ++kt)
                #pragma unroll
                for (int nt = 0; nt < 4; ++nt) {
                    half8 bfr = *(const half8*)(wrec + nt * 16384 + j0 * 128 + swz[kt]);
                    acc[nt] = __builtin_amdgcn_mfma_f32_16x16x32_f16(ah[kt], bfr, acc[nt], 0, 0, 0);
                }
            #pragma unroll
            for (int kt = 0; kt < 2; ++kt) {
                half8 axk = kt ? ax1 : ax0;
                #pragma unroll
                for (int nt = 0; nt < 4; ++nt)
                    acc[nt] = __builtin_amdgcn_mfma_f32_16x16x32_f16(axk, wresf[nt][kt], acc[nt], 0, 0, 0);
            }

            {   // prefetch x(t+1)
                int tn = (t + 1 < T_STEPS) ? t + 1 : t;
                if constexpr (XH) {
                    const _Float16* xq = xph + (size_t)tn * (BATCH * DIN);
                    nxh0 = *(const half8*)(xq);
                    nxh1 = *(const half8*)(xq + 32);
                } else {
                    const float* xq = xpf + (size_t)tn * (BATCH * DIN);
                    nxf0 = *(const f32x4*)(xq);      nxf1 = *(const f32x4*)(xq + 4);
                    nxf2 = *(const f32x4*)(xq + 32); nxf3 = *(const f32x4*)(xq + 36);
                }
            }

            _Float16* slabT = slab + (size_t)(t * 16 + tile) * 2048;
            #pragma unroll
            for (int i = 0; i < 4; ++i) {
                float ig = sig2(acc[0][i]);
                float fg = sig2(acc[1][i]);
                float gg = tanh2(acc[2][i]);
                float og = sig2(acc[3][i]);
                float c  = fg * cc[i] + ig * gg;
                cc[i] = c;
                _Float16 hf = (_Float16)(og * tanh_c(c));
                hdb[cbo + w0off[i]] = hf;                       // swizzled, for recurrence
                slabT[(quad * 4 + i) * 128 + j0] = hf;          // unswizzled FIFO slot
            }
        }
        __syncthreads();
        if (tid == 0)
            __hip_atomic_store(flags + (T_STEPS - 1) * 16 + tile, T_STEPS,
                               __ATOMIC_RELEASE, __HIP_MEMORY_SCOPE_AGENT);
    } else {
        // ================= layer-1 consumer + head =================
        if (tid == 0) {
            while (__hip_atomic_load(flags + tile, __ATOMIC_ACQUIRE,
                                     __HIP_MEMORY_SCOPE_AGENT) < 1)
                __builtin_amdgcn_s_sleep(1);
        }
        #pragma unroll 1
        for (int t = 0; t < T_STEPS; ++t) {
            const int pbo = (t & 1) * 2048, cbo = pbo ^ 2048;
            __syncthreads();   // poll(t) confirmed + t-1 LDS writes visible

            const _Float16* slabT = slab + (size_t)(t * 16 + tile) * 2048;
            half8 a0[4], a1[4];
            #pragma unroll
            for (int kt = 0; kt < 4; ++kt)
                a0[kt] = *(const half8*)(slabT + col * 128 + kt * 32 + quad * 8);
            #pragma unroll
            for (int kt = 0; kt < 4; ++kt)
                a1[kt] = *(const half8*)(hdb + pbo + hoff[kt]);

            // poll flag(t+1) early: overlaps this step's compute (wave 0 only)
            if (tid == 0 && t + 1 < T_STEPS) {
                while (__hip_atomic_load(flags + (t + 1) * 16 + tile, __ATOMIC_ACQUIRE,
                                         __HIP_MEMORY_SCOPE_AGENT) < t + 2)
                    __builtin_amdgcn_s_sleep(1);
            }

            f32x4 acc[4];
            #pragma unroll
            for (int nt = 0; nt < 4; ++nt) {
                f32x4 b = {bias[nt], bias[nt], bias[nt], bias[nt]};
                acc[nt] = b;
            }
            // recurrent part first (LDS data, hides a0 global latency)
            #pragma unroll
            for (int kt = 0; kt < 4; ++kt)
                #pragma unroll
                for (int nt = 0; nt < 4; ++nt) {
                    half8 bfr = *(const half8*)(wrec + nt * 16384 + j0 * 128 + swz[kt]);
                    acc[nt] = __builtin_amdgcn_mfma_f32_16x16x32_f16(a1[kt], bfr, acc[nt], 0, 0, 0);
                }
            #pragma unroll
            for (int kt = 0; kt < 4; ++kt)
                #pragma unroll
                for (int nt = 0; nt < 4; ++nt)
                    acc[nt] = __builtin_amdgcn_mfma_f32_16x16x32_f16(a0[kt], wresf[nt][kt], acc[nt], 0, 0, 0);

            #pragma unroll
            for (int i = 0; i < 4; ++i) {
                float ig = sig2(acc[0][i]);
                float fg = sig2(acc[1][i]);
                float gg = tanh2(acc[2][i]);
                float og = sig2(acc[3][i]);
                float c  = fg * cc[i] + ig * gg;
                cc[i] = c;
                hdb[cbo + w0off[i]] = (_Float16)(og * tanh_c(c));
            }

            // value head for step t-1 on wave 7 (reads pbo buffer = h1(t-1))
            if (w == 7) {
                f32x4 vh = {0.f, 0.f, 0.f, 0.f};
                #pragma unroll
                for (int kt = 0; kt < 4; ++kt) {
                    half8 av = *(const half8*)(hdb + pbo + hoff[kt]);
                    half8 bw = *(const half8*)(woutl + kt * 32 + quad * 8);
                    if (col != 0) {
                        #pragma unroll
                        for (int jj = 0; jj < 8; ++jj) bw[jj] = (_Float16)0.0f;
                    }
                    vh = __builtin_amdgcn_mfma_f32_16x16x32_f16(av, bw, vh, 0, 0, 0);
                }
                if (t > 0 && col == 0) {
                    f32x4 vo = {vh[0] + bout, vh[1] + bout, vh[2] + bout, vh[3] + bout};
                    *(f32x4*)(out + (size_t)(t - 1) * BATCH + rowbase + quad * 4) = vo;
                }
            }
        }
        __syncthreads();
        if (w == 7) {   // head for t = T-1
            const int fbo = (((T_STEPS - 1) & 1) ^ 1) * 2048;
            f32x4 vh = {0.f, 0.f, 0.f, 0.f};
            #pragma unroll
            for (int kt = 0; kt < 4; ++kt) {
                half8 av = *(const half8*)(hdb + fbo + hoff[kt]);
                half8 bw = *(const half8*)(woutl + kt * 32 + quad * 8);
                if (col != 0) {
                    #pragma unroll
                    for (int jj = 0; jj < 8; ++jj) bw[jj] = (_Float16)0.0f;
                }
                vh = __builtin_amdgcn_mfma_f32_16x16x32_f16(av, bw, vh, 0, 0, 0);
            }
            if (col == 0) {
                f32x4 vo = {vh[0] + bout, vh[1] + bout, vh[2] + bout, vh[3] + bout};
                *(f32x4*)(out + (size_t)(T_STEPS - 1) * BATCH + rowbase + quad * 4) = vo;
            }
        }
    }
}

// =====================  monolithic fallback (R2 structure, scaled act)  =====
#define MONO_LDS_BYTES ((73728 + 128) * 2)

template<bool XH>
__global__ __launch_bounds__(512, 2) void lstm_mono(
        const float* __restrict__ state32, const _Float16* __restrict__ wsw,
        const float* __restrict__ b_ih0, const float* __restrict__ b_hh0,
        const float* __restrict__ b_ih1, const float* __restrict__ b_hh1,
        const float* __restrict__ w_out, const float* __restrict__ b_out,
        float* __restrict__ out) {
    extern __shared__ _Float16 lds[];
    _Float16* whh1  = lds;
    _Float16* h0b   = lds + 65536;
    _Float16* h1b   = lds + 69632;
    _Float16* woutl = lds + 73728;

    const int tid  = threadIdx.x;
    const int w    = tid >> 6;
    const int lane = tid & 63;
    const int col  = lane & 15;
    const int quad = lane >> 4;
    const int rowbase = blockIdx.x * 16;
    const int j0 = w * 16 + col;

    const _Float16* whh1g = wsw + WH_HH1;
    #pragma unroll
    for (int it = 0; it < 16; ++it) {
        int flat = (it * 512 + tid) * 8;
        int r = flat >> 7, chunk = (flat >> 3) & 15;
        *(half8*)(whh1 + r * 128 + ((chunk ^ (r & 15)) * 8)) = *(const half8*)(whh1g + flat);
    }
    {
        half8 z;
        #pragma unroll
        for (int jj = 0; jj < 8; ++jj) z[jj] = (_Float16)0.0f;
        for (int i = tid * 8; i < 8192; i += 4096) *(half8*)(h0b + i) = z;
    }
    if (tid < 128) woutl[tid] = (_Float16)w_out[tid];

    half8 whh0f[4][4], wih1f[4][4];
    float bias0[4], bias1[4];
    #pragma unroll
    for (int nt = 0; nt < 4; ++nt) {
        int j = nt * 128 + j0;
        float sc = (nt == 2) ? LOG2E2 : LOG2E;
        #pragma unroll
        for (int kt = 0; kt < 4; ++kt) {
            whh0f[nt][kt] = *(const half8*)(wsw + WH_HH0 + j * 128 + kt * 32 + quad * 8);
            wih1f[nt][kt] = *(const half8*)(wsw + WH_IH1 + j * 128 + kt * 32 + quad * 8);
        }
        bias0[nt] = (b_ih0[j] + b_hh0[j]) * sc;
        bias1[nt] = (b_ih1[j] + b_hh1[j]) * sc;
    }
    const float bout = b_out[0];

    int swz[4], hoff[4], w0off[4];
    #pragma unroll
    for (int kt = 0; kt < 4; ++kt) {
        swz[kt]  = ((kt * 4 + quad) ^ col) * 8;
        hoff[kt] = col * 128 + swz[kt];
    }
    #pragma unroll
    for (int i = 0; i < 4; ++i) {
        int row = quad * 4 + i;
        w0off[i] = row * 128 + (((2 * w + (col >> 3)) ^ row) * 8) + (col & 7);
    }
    float c0[4] = {0.f,0.f,0.f,0.f}, c1[4] = {0.f,0.f,0.f,0.f};

    const _Float16* xph = wsw + WH_X2 + (size_t)(rowbase + col) * DIN + quad * 8;
    const float*    xpf = state32 + (size_t)(rowbase + col) * DIN + quad * 8;
    half8 nxh0, nxh1;
    f32x4 nxf0, nxf1, nxf2, nxf3;
    if constexpr (XH) {
        nxh0 = *(const half8*)(xph); nxh1 = *(const half8*)(xph + 32);
    } else {
        nxf0 = *(const f32x4*)(xpf);      nxf1 = *(const f32x4*)(xpf + 4);
        nxf2 = *(const f32x4*)(xpf + 32); nxf3 = *(const f32x4*)(xpf + 36);
    }
    __syncthreads();
    const _Float16* wih0g = wsw + WH_IH0;

    #pragma unroll 1
    for (int t = 0; t < T_STEPS; ++t) {
        const int pbo = (t & 1) * 2048, cbo = pbo ^ 2048;
        half8 ax0, ax1;
        if constexpr (XH) { ax0 = nxh0; ax1 = nxh1; }
        else {
            #pragma unroll
            for (int jj = 0; jj < 4; ++jj) {
                ax0[jj]   = (_Float16)nxf0[jj]; ax0[jj+4] = (_Float16)nxf1[jj];
                ax1[jj]   = (_Float16)nxf2[jj]; ax1[jj+4] = (_Float16)nxf3[jj];
            }
        }
        half8 wif[4][2];
        #pragma unroll
        for (int nt = 0; nt < 4; ++nt)
            #pragma unroll
            for (int kt = 0; kt < 2; ++kt)
                wif[nt][kt] = *(const half8*)(wih0g + (nt * 128 + j0) * 64 + kt * 32 + quad * 8);
        half8 ah[4];
        #pragma unroll
        for (int kt = 0; kt < 4; ++kt)
            ah[kt] = *(const half8*)(h0b + pbo + hoff[kt]);

        f32x4 acc[4];
        #pragma unroll
        for (int nt = 0; nt < 4; ++nt) {
            f32x4 b = {bias0[nt], bias0[nt], bias0[nt], bias0[nt]};
            acc[nt] = b;
        }
        #pragma unroll
        for (int kt = 0; kt < 4; ++kt)
            #pragma unroll
            for (int nt = 0; nt < 4; ++nt)
                acc[nt] = __builtin_amdgcn_mfma_f32_16x16x32_f16(ah[kt], whh0f[nt][kt], acc[nt], 0, 0, 0);
        #pragma unroll
        for (int kt = 0; kt < 2; ++kt) {
            half8 axk = kt ? ax1 : ax0;
            #pragma unroll
            for (int nt = 0; nt < 4; ++nt)
                acc[nt] = __builtin_amdgcn_mfma_f32_16x16x32_f16(axk, wif[nt][kt], acc[nt], 0, 0, 0);
        }
        {
            int tn = (t + 1 < T_STEPS) ? t + 1 : t;
            if constexpr (XH) {
                const _Float16* xq = xph + (size_t)tn * (BATCH * DIN);
                nxh0 = *(const half8*)(xq); nxh1 = *(const half8*)(xq + 32);
            } else {
                const float* xq = xpf + (size_t)tn * (BATCH * DIN);
                nxf0 = *(const f32x4*)(xq);      nxf1 = *(const f32x4*)(xq + 4);
                nxf2 = *(const f32x4*)(xq + 32); nxf3 = *(const f32x4*)(xq + 36);
            }
        }
        #pragma unroll
        for (int i = 0; i < 4; ++i) {
            float ig = sig2(acc[0][i]);
            float fg = sig2(acc[1][i]);
            float gg = tanh2(acc[2][i]);
            float og = sig2(acc[3][i]);
            float c  = fg * c0[i] + ig * gg;
            c0[i] = c;
            h0b[cbo + w0off[i]] = (_Float16)(og * tanh_c(c));
        }
        __syncthreads();

        #pragma unroll
        for (int nt = 0; nt < 4; ++nt) {
            f32x4 b = {bias1[nt], bias1[nt], bias1[nt], bias1[nt]};
            acc[nt] = b;
        }
        #pragma unroll
        for (int kt = 0; kt < 4; ++kt) {
            half8 a0 = *(const half8*)(h0b + cbo + hoff[kt]);
            half8 a1 = *(const half8*)(h1b + pbo + hoff[kt]);
            #pragma unroll
            for (int nt = 0; nt < 4; ++nt)
                acc[nt] = __builtin_amdgcn_mfma_f32_16x16x32_f16(a0, wih1f[nt][kt], acc[nt], 0, 0, 0);
            #pragma unroll
            for (int nt = 0; nt < 4; ++nt) {
                half8 bfr = *(const half8*)(whh1 + nt * 16384 + j0 * 128 + swz[kt]);
                acc[nt] = __builtin_amdgcn_mfma_f32_16x16x32_f16(a1, bfr, acc[nt], 0, 0, 0);
            }
        }
        #pragma unroll
        for (int i = 0; i < 4; ++i) {
            float ig = sig2(acc[0][i]);
            float fg = sig2(acc[1][i]);
            float gg = tanh2(acc[2][i]);
            float og = sig2(acc[3][i]);
            float c  = fg * c1[i] + ig * gg;
            c1[i] = c;
            h1b[cbo + w0off[i]] = (_Float16)(og * tanh_c(c));
        }
        if (w == 7) {
            f32x4 vh = {0.f, 0.f, 0.f, 0.f};
            #pragma unroll
            for (int kt = 0; kt < 4; ++kt) {
                half8 a1 = *(const half8*)(h1b + pbo + hoff[kt]);
                half8 bw = *(const half8*)(woutl + kt * 32 + quad * 8);
                if (col != 0) {
                    #pragma unroll
                    for (int jj = 0; jj < 8; ++jj) bw[jj] = (_Float16)0.0f;
                }
                vh = __builtin_amdgcn_mfma_f32_16x16x32_f16(a1, bw, vh, 0, 0, 0);
            }
            if (t > 0 && col == 0) {
                f32x4 vo = {vh[0] + bout, vh[1] + bout, vh[2] + bout, vh[3] + bout};
                *(f32x4*)(out + (size_t)(t - 1) * BATCH + rowbase + quad * 4) = vo;
            }
        }
    }
    __syncthreads();
    if (w == 7) {
        const int fbo = (((T_STEPS - 1) & 1) ^ 1) * 2048;
        f32x4 vh = {0.f, 0.f, 0.f, 0.f};
        #pragma unroll
        for (int kt = 0; kt < 4; ++kt) {
            half8 a1 = *(const half8*)(h1b + fbo + hoff[kt]);
            half8 bw = *(const half8*)(woutl + kt * 32 + quad * 8);
            if (col != 0) {
                #pragma unroll
                for (int jj = 0; jj < 8; ++jj) bw[jj] = (_Float16)0.0f;
            }
            vh = __builtin_amdgcn_mfma_f32_16x16x32_f16(a1, bw, vh, 0, 0, 0);
        }
        if (col == 0) {
            f32x4 vo = {vh[0] + bout, vh[1] + bout, vh[2] + bout, vh[3] + bout};
            *(f32x4*)(out + (size_t)(T_STEPS - 1) * BATCH + rowbase + quad * 4) = vo;
        }
    }
}

extern "C" void kernel_launch(void* const* d_in, const int* in_sizes, int n_in,
                              void* d_out, int out_size, void* d_ws, size_t ws_size,
                              hipStream_t stream) {
    const float* state = (const float*)d_in[0];
    const float* wih0  = (const float*)d_in[1];
    const float* whh0  = (const float*)d_in[2];
    const float* bih0  = (const float*)d_in[3];
    const float* bhh0  = (const float*)d_in[4];
    const float* wih1  = (const float*)d_in[5];
    const float* whh1  = (const float*)d_in[6];
    const float* bih1  = (const float*)d_in[7];
    const float* bhh1  = (const float*)d_in[8];
    const float* wout  = (const float*)d_in[9];
    const float* bout  = (const float*)d_in[10];
    _Float16* wsh = (_Float16*)d_ws;
    float* outp = (float*)d_out;

    prep_weights<<<896, 256, 0, stream>>>(wih0, whh0, wih1, whh1, wsh);

    if (ws_size >= WS2_TOTAL) {
        prep_state<<<4096, 256, 0, stream>>>(state, wsh + WH_X2);
        lstm_pipe<true><<<32, 512, PIPE_LDS_BYTES, stream>>>(
            state, wsh, bih0, bhh0, bih1, bhh1, wout, bout,
            wsh + WH_SLAB2, (int*)((char*)d_ws + WB_FLAG2), wsh + WH_X2, outp);
    } else if (ws_size >= WS1_TOTAL) {
        lstm_pipe<false><<<32, 512, PIPE_LDS_BYTES, stream>>>(
            state, wsh, bih0, bhh0, bih1, bhh1, wout, bout,
            wsh + WH_SLAB1, (int*)((char*)d_ws + WB_FLAG1), nullptr, outp);
    } else if (ws_size >= WS0XH_TOTAL) {
        prep_state<<<4096, 256, 0, stream>>>(state, wsh + WH_X2);
        lstm_mono<true><<<16, 512, MONO_LDS_BYTES, stream>>>(
            state, wsh, bih0, bhh0, bih1, bhh1, wout, bout, outp);
    } else {
        lstm_mono<false><<<16, 512, MONO_LDS_BYTES, stream>>>(
            state, wsh, bih0, bhh0, bih1, bhh1, wout, bout, outp);
    }
}

// Round 4
// 714.134 us; speedup vs baseline: 2.7009x; 1.4312x over previous
//
#include <hip/hip_runtime.h>

// LSTM_Critic: T=512, B=256, D_IN=64, H=128. Round-4: layer-pipelined
// persistent kernel (32 WGs x 512 thr: 16 producers L0, 16 consumers L1+head)
// with GROUP-BATCHED handoff:
//  - release/acquire (agent scope, cross-XCD safe) once per 16 steps, not per
//    step -> L2 wbl2/inv cost amortized 16x (R3: per-step fences = ~0.9us/step).
//  - consumer register-prefetches slab slot t+1 (latency fully hidden);
//    next-group flag polled at local step 12, barrier-ordered before use.
//  - producer defers slab store of h(t) to top of step t+1 (full step of
//    slack before the barrier vmcnt drain), except at group end.
// FIFO slots are written-once/read-once -> relaxed caching is safe; flags
// poison (0xAAAAAAAA) is negative -> reads as "not ready" deterministically.

#define T_STEPS 512
#define BATCH   256
#define DIN     64
#define GROUP   16
#define NGRP    (T_STEPS / GROUP)

typedef _Float16 half8 __attribute__((ext_vector_type(8)));
typedef float    f32x4 __attribute__((ext_vector_type(4)));

#define LOG2E  1.44269504088896f
#define LOG2E2 2.88539008177793f

// ---- ws layout (fp16 element offsets unless noted) ----
#define WH_IH0 0          // [512][64]
#define WH_HH0 32768      // [512][128]
#define WH_IH1 98304      // [512][128]
#define WH_HH1 163840     // [512][128]
// mode 2: + fp16 x + slab + flags
#define WH_X2     229376                   // 8388608 halfs
#define WH_SLAB2  8617984                  // 16777216 halfs
#define WB_FLAG2  50790400                 // byte offset, 8192 ints reserved
#define WS2_TOTAL 50823168
// mode 1: + slab + flags (x stays fp32 from input)
#define WH_SLAB1  229376
#define WB_FLAG1  34013184
#define WS1_TOTAL 34045952
// mode 0 (monolithic): optional fp16 x at WH_X2
#define WS0XH_TOTAL ((size_t)(WH_X2 + 8388608) * 2)

__global__ void prep_weights(const float* __restrict__ wih0,
                             const float* __restrict__ whh0,
                             const float* __restrict__ wih1,
                             const float* __restrict__ whh1,
                             _Float16* __restrict__ ws) {
    int idx = blockIdx.x * 256 + threadIdx.x;   // 229376 total
    float v; int row;
    if (idx < 32768)       { row = idx >> 6;             v = wih0[idx]; }
    else if (idx < 98304)  { row = (idx - 32768) >> 7;   v = whh0[idx - 32768]; }
    else if (idx < 163840) { row = (idx - 98304) >> 7;   v = wih1[idx - 98304]; }
    else                   { row = (idx - 163840) >> 7;  v = whh1[idx - 163840]; }
    // gate chunk 2 (g) uses tanh -> scale 2*log2e; others sigmoid -> log2e
    float sc = ((row >> 7) == 2) ? LOG2E2 : LOG2E;
    ws[idx] = (_Float16)(v * sc);
}

__global__ void prep_state(const float* __restrict__ s, _Float16* __restrict__ d) {
    int i = (blockIdx.x * 256 + threadIdx.x) * 8;   // 8388608 elements
    f32x4 a = *(const f32x4*)(s + i);
    f32x4 b = *(const f32x4*)(s + i + 4);
    half8 h;
    h[0]=(_Float16)a[0]; h[1]=(_Float16)a[1]; h[2]=(_Float16)a[2]; h[3]=(_Float16)a[3];
    h[4]=(_Float16)b[0]; h[5]=(_Float16)b[1]; h[6]=(_Float16)b[2]; h[7]=(_Float16)b[3];
    *(half8*)(d + i) = h;
}

// activations on pre-scaled gate values
__device__ __forceinline__ float sig2(float y) {        // y = x*log2e
    return __builtin_amdgcn_rcpf(1.0f + __builtin_amdgcn_exp2f(-y));
}
__device__ __forceinline__ float tanh2(float y2) {      // y2 = x*2*log2e
    return 1.0f - 2.0f * __builtin_amdgcn_rcpf(1.0f + __builtin_amdgcn_exp2f(y2));
}
__device__ __forceinline__ float tanh_c(float c) {      // c unscaled
    return 1.0f - 2.0f * __builtin_amdgcn_rcpf(1.0f + __builtin_amdgcn_exp2f(c * LOG2E2));
}

// =====================  pipelined kernel  =====================
// LDS (halfs): wrec[512][128] swizzled = 65536 | hdb[2][16][128] = 4096 | woutl[128]
#define PIPE_LDS_BYTES ((65536 + 4096 + 128) * 2)

template<bool XH>
__global__ __launch_bounds__(512, 1) void lstm_pipe(
        const float* __restrict__ state32, const _Float16* __restrict__ wsw,
        const float* __restrict__ b_ih0, const float* __restrict__ b_hh0,
        const float* __restrict__ b_ih1, const float* __restrict__ b_hh1,
        const float* __restrict__ w_out, const float* __restrict__ b_out,
        _Float16* __restrict__ slab, int* __restrict__ flags,
        const _Float16* __restrict__ xh, float* __restrict__ out) {
    extern __shared__ _Float16 lds[];
    _Float16* wrec  = lds;            // recurrent weights (whh0 / whh1), swizzled
    _Float16* hdb   = lds + 65536;    // h double-buffer [2][16][128], swizzled
    _Float16* woutl = lds + 69632;    // head weights (consumer)

    const int tid  = threadIdx.x;
    const int w    = tid >> 6;
    const int lane = tid & 63;
    const int col  = lane & 15;
    const int quad = lane >> 4;
    const bool producer = blockIdx.x < 16;
    const int tile = blockIdx.x & 15;
    const int rowbase = tile * 16;
    const int j0 = w * 16 + col;

    // ---- one-time LDS init ----
    const _Float16* wrg = wsw + (producer ? WH_HH0 : WH_HH1);
    #pragma unroll
    for (int it = 0; it < 16; ++it) {
        int flat = (it * 512 + tid) * 8;
        int r = flat >> 7, chunk = (flat >> 3) & 15;
        *(half8*)(wrec + r * 128 + ((chunk ^ (r & 15)) * 8)) = *(const half8*)(wrg + flat);
    }
    {
        half8 z;
        #pragma unroll
        for (int jj = 0; jj < 8; ++jj) z[jj] = (_Float16)0.0f;
        *(half8*)(hdb + tid * 8) = z;   // 512*8 = 4096 halfs
    }
    if (!producer && tid < 128) woutl[tid] = (_Float16)w_out[tid];

    // ---- resident input-side B-frags + scaled biases ----
    half8 wresf[4][4];   // producer uses [nt][0..1] (wih0), consumer [nt][0..3] (wih1)
    float bias[4];
    #pragma unroll
    for (int nt = 0; nt < 4; ++nt) {
        int j = nt * 128 + j0;
        float sc = (nt == 2) ? LOG2E2 : LOG2E;
        if (producer) {
            #pragma unroll
            for (int kt = 0; kt < 2; ++kt)
                wresf[nt][kt] = *(const half8*)(wsw + WH_IH0 + j * 64 + kt * 32 + quad * 8);
            bias[nt] = (b_ih0[j] + b_hh0[j]) * sc;
        } else {
            #pragma unroll
            for (int kt = 0; kt < 4; ++kt)
                wresf[nt][kt] = *(const half8*)(wsw + WH_IH1 + j * 128 + kt * 32 + quad * 8);
            bias[nt] = (b_ih1[j] + b_hh1[j]) * sc;
        }
    }
    const float bout = b_out[0];

    // swizzled-address precompute (R2-verified, 0 bank conflicts)
    int swz[4], hoff[4], w0off[4];
    #pragma unroll
    for (int kt = 0; kt < 4; ++kt) {
        swz[kt]  = ((kt * 4 + quad) ^ col) * 8;
        hoff[kt] = col * 128 + swz[kt];
    }
    #pragma unroll
    for (int i = 0; i < 4; ++i) {
        int row = quad * 4 + i;
        w0off[i] = row * 128 + (((2 * w + (col >> 3)) ^ row) * 8) + (col & 7);
    }
    float cc[4] = {0.f, 0.f, 0.f, 0.f};

    __syncthreads();

    if (producer) {
        // ================= layer-0 producer =================
        const _Float16* xph = xh + (size_t)(rowbase + col) * DIN + quad * 8;
        const float*    xpf = state32 + (size_t)(rowbase + col) * DIN + quad * 8;
        half8 nxh0, nxh1;
        f32x4 nxf0, nxf1, nxf2, nxf3;
        if constexpr (XH) {
            nxh0 = *(const half8*)(xph);
            nxh1 = *(const half8*)(xph + 32);
        } else {
            nxf0 = *(const f32x4*)(xpf);      nxf1 = *(const f32x4*)(xpf + 4);
            nxf2 = *(const f32x4*)(xpf + 32); nxf3 = *(const f32x4*)(xpf + 36);
        }
        _Float16 hh[4];   // held h(t-1), stored at top of step t

        #pragma unroll 1
        for (int t = 0; t < T_STEPS; ++t) {
            const int pbo = (t & 1) * 2048, cbo = pbo ^ 2048;
            const int lt = t & (GROUP - 1);
            __syncthreads();   // t-1 LDS writes visible; vmcnt drained

            if (lt == 0) {
                // group (t/GROUP - 1) fully stored + drained -> publish
                if (t > 0 && tid == 0)
                    __hip_atomic_store(flags + (t / GROUP - 1) * 16 + tile, t / GROUP,
                                       __ATOMIC_RELEASE, __HIP_MEMORY_SCOPE_AGENT);
            } else {
                // deferred slab store of h(t-1): full step before next drain
                _Float16* slabP = slab + (size_t)((t - 1) * 16 + tile) * 2048;
                #pragma unroll
                for (int i = 0; i < 4; ++i)
                    slabP[(quad * 4 + i) * 128 + j0] = hh[i];
            }

            half8 ax0, ax1;
            if constexpr (XH) { ax0 = nxh0; ax1 = nxh1; }
            else {
                #pragma unroll
                for (int jj = 0; jj < 4; ++jj) {
                    ax0[jj]   = (_Float16)nxf0[jj]; ax0[jj+4] = (_Float16)nxf1[jj];
                    ax1[jj]   = (_Float16)nxf2[jj]; ax1[jj+4] = (_Float16)nxf3[jj];
                }
            }
            half8 ah[4];
            #pragma unroll
            for (int kt = 0; kt < 4; ++kt)
                ah[kt] = *(const half8*)(hdb + pbo + hoff[kt]);

            f32x4 acc[4];
            #pragma unroll
            for (int nt = 0; nt < 4; ++nt) {
                f32x4 b = {bias[nt], bias[nt], bias[nt], bias[nt]};
                acc[nt] = b;
            }
            #pragma unroll
            for (int kt = 0; kt < 4; ++kt)
                #pragma unroll
                for (int nt = 0; nt < 4; ++nt) {
                    half8 bfr = *(const half8*)(wrec + nt * 16384 + j0 * 128 + swz[kt]);
                    acc[nt] = __builtin_amdgcn_mfma_f32_16x16x32_f16(ah[kt], bfr, acc[nt], 0, 0, 0);
                }
            #pragma unroll
            for (int kt = 0; kt < 2; ++kt) {
                half8 axk = kt ? ax1 : ax0;
                #pragma unroll
                for (int nt = 0; nt < 4; ++nt)
                    acc[nt] = __builtin_amdgcn_mfma_f32_16x16x32_f16(axk, wresf[nt][kt], acc[nt], 0, 0, 0);
            }

            {   // prefetch x(t+1)
                int tn = (t + 1 < T_STEPS) ? t + 1 : t;
                if constexpr (XH) {
                    const _Float16* xq = xph + (size_t)tn * (BATCH * DIN);
                    nxh0 = *(const half8*)(xq);
                    nxh1 = *(const half8*)(xq + 32);
                } else {
                    const float* xq = xpf + (size_t)tn * (BATCH * DIN);
                    nxf0 = *(const f32x4*)(xq);      nxf1 = *(const f32x4*)(xq + 4);
                    nxf2 = *(const f32x4*)(xq + 32); nxf3 = *(const f32x4*)(xq + 36);
                }
            }

            _Float16* slabT = slab + (size_t)(t * 16 + tile) * 2048;
            #pragma unroll
            for (int i = 0; i < 4; ++i) {
                float ig = sig2(acc[0][i]);
                float fg = sig2(acc[1][i]);
                float gg = tanh2(acc[2][i]);
                float og = sig2(acc[3][i]);
                float c  = fg * cc[i] + ig * gg;
                cc[i] = c;
                _Float16 hf = (_Float16)(og * tanh_c(c));
                hdb[cbo + w0off[i]] = hf;                       // swizzled, recurrence
                if (lt == GROUP - 1)
                    slabT[(quad * 4 + i) * 128 + j0] = hf;      // group end: store now
                else
                    hh[i] = hf;                                 // defer to next step
            }
        }
        __syncthreads();   // drain group-end stores of h(T-1)
        if (tid == 0)
            __hip_atomic_store(flags + (NGRP - 1) * 16 + tile, NGRP,
                               __ATOMIC_RELEASE, __HIP_MEMORY_SCOPE_AGENT);
    } else {
        // ================= layer-1 consumer + head =================
        if (tid == 0) {   // wait for group 0
            while (__hip_atomic_load(flags + tile, __ATOMIC_ACQUIRE,
                                     __HIP_MEMORY_SCOPE_AGENT) < 1)
                __builtin_amdgcn_s_sleep(1);
        }
        __syncthreads();   // order acquire before all waves' slab loads

        half8 curA[4], nextA[4];
        {   // prefetch slot 0
            const _Float16* s0 = slab + (size_t)tile * 2048;
            #pragma unroll
            for (int kt = 0; kt < 4; ++kt)
                curA[kt] = *(const half8*)(s0 + col * 128 + kt * 32 + quad * 8);
        }

        #pragma unroll 1
        for (int t = 0; t < T_STEPS; ++t) {
            const int pbo = (t & 1) * 2048, cbo = pbo ^ 2048;
            const int lt = t & (GROUP - 1);
            __syncthreads();   // t-1 LDS writes visible; orders any prior acquire

            half8 a1[4];
            #pragma unroll
            for (int kt = 0; kt < 4; ++kt)
                a1[kt] = *(const half8*)(hdb + pbo + hoff[kt]);

            f32x4 acc[4];
            #pragma unroll
            for (int nt = 0; nt < 4; ++nt) {
                f32x4 b = {bias[nt], bias[nt], bias[nt], bias[nt]};
                acc[nt] = b;
            }
            // recurrent part (LDS) first
            #pragma unroll
            for (int kt = 0; kt < 4; ++kt)
                #pragma unroll
                for (int nt = 0; nt < 4; ++nt) {
                    half8 bfr = *(const half8*)(wrec + nt * 16384 + j0 * 128 + swz[kt]);
                    acc[nt] = __builtin_amdgcn_mfma_f32_16x16x32_f16(a1[kt], bfr, acc[nt], 0, 0, 0);
                }
            // input part: h0(t) from prefetched registers
            #pragma unroll
            for (int kt = 0; kt < 4; ++kt)
                #pragma unroll
                for (int nt = 0; nt < 4; ++nt)
                    acc[nt] = __builtin_amdgcn_mfma_f32_16x16x32_f16(curA[kt], wresf[nt][kt], acc[nt], 0, 0, 0);

            // poll NEXT group's flag mid-group; barrier at t+1 orders it for
            // the cross-boundary prefetch issued at lt == GROUP-1
            if (lt == 12 && tid == 0) {
                int g1 = (t >> 4) + 1;
                if (g1 < NGRP) {
                    while (__hip_atomic_load(flags + g1 * 16 + tile, __ATOMIC_ACQUIRE,
                                             __HIP_MEMORY_SCOPE_AGENT) < g1 + 1)
                        __builtin_amdgcn_s_sleep(1);
                }
            }

            {   // prefetch slab slot t+1 (flag for its group already confirmed)
                int tn = (t + 1 < T_STEPS) ? t + 1 : t;
                const _Float16* sq = slab + (size_t)(tn * 16 + tile) * 2048;
                #pragma unroll
                for (int kt = 0; kt < 4; ++kt)
                    nextA[kt] = *(const half8*)(sq + col * 128 + kt * 32 + quad * 8);
            }

            #pragma unroll
            for (int i = 0; i < 4; ++i) {
                float ig = sig2(acc[0][i]);
                float fg = sig2(acc[1][i]);
                float gg = tanh2(acc[2][i]);
                float og = sig2(acc[3][i]);
                float c  = fg * cc[i] + ig * gg;
                cc[i] = c;
                hdb[cbo + w0off[i]] = (_Float16)(og * tanh_c(c));
            }

            // value head for step t-1 on wave 7 (reads pbo buffer = h1(t-1))
            if (w == 7) {
                f32x4 vh = {0.f, 0.f, 0.f, 0.f};
                #pragma unroll
                for (int kt = 0; kt < 4; ++kt) {
                    half8 av = *(const half8*)(hdb + pbo + hoff[kt]);
                    half8 bw = *(const half8*)(woutl + kt * 32 + quad * 8);
                    if (col != 0) {
                        #pragma unroll
                        for (int jj = 0; jj < 8; ++jj) bw[jj] = (_Float16)0.0f;
                    }
                    vh = __builtin_amdgcn_mfma_f32_16x16x32_f16(av, bw, vh, 0, 0, 0);
                }
                if (t > 0 && col == 0) {
                    f32x4 vo = {vh[0] + bout, vh[1] + bout, vh[2] + bout, vh[3] + bout};
                    *(f32x4*)(out + (size_t)(t - 1) * BATCH + rowbase + quad * 4) = vo;
                }
            }

            #pragma unroll
            for (int kt = 0; kt < 4; ++kt) curA[kt] = nextA[kt];
        }
        __syncthreads();
        if (w == 7) {   // head for t = T-1
            const int fbo = (((T_STEPS - 1) & 1) ^ 1) * 2048;
            f32x4 vh = {0.f, 0.f, 0.f, 0.f};
            #pragma unroll
            for (int kt = 0; kt < 4; ++kt) {
                half8 av = *(const half8*)(hdb + fbo + hoff[kt]);
                half8 bw = *(const half8*)(woutl + kt * 32 + quad * 8);
                if (col != 0) {
                    #pragma unroll
                    for (int jj = 0; jj < 8; ++jj) bw[jj] = (_Float16)0.0f;
                }
                vh = __builtin_amdgcn_mfma_f32_16x16x32_f16(av, bw, vh, 0, 0, 0);
            }
            if (col == 0) {
                f32x4 vo = {vh[0] + bout, vh[1] + bout, vh[2] + bout, vh[3] + bout};
                *(f32x4*)(out + (size_t)(T_STEPS - 1) * BATCH + rowbase + quad * 4) = vo;
            }
        }
    }
}

// =====================  monolithic fallback (R2 structure, scaled act)  =====
#define MONO_LDS_BYTES ((73728 + 128) * 2)

template<bool XH>
__global__ __launch_bounds__(512, 2) void lstm_mono(
        const float* __restrict__ state32, const _Float16* __restrict__ wsw,
        const float* __restrict__ b_ih0, const float* __restrict__ b_hh0,
        const float* __restrict__ b_ih1, const float* __restrict__ b_hh1,
        const float* __restrict__ w_out, const float* __restrict__ b_out,
        float* __restrict__ out) {
    extern __shared__ _Float16 lds[];
    _Float16* whh1  = lds;
    _Float16* h0b   = lds + 65536;
    _Float16* h1b   = lds + 69632;
    _Float16* woutl = lds + 73728;

    const int tid  = threadIdx.x;
    const int w    = tid >> 6;
    const int lane = tid & 63;
    const int col  = lane & 15;
    const int quad = lane >> 4;
    const int rowbase = blockIdx.x * 16;
    const int j0 = w * 16 + col;

    const _Float16* whh1g = wsw + WH_HH1;
    #pragma unroll
    for (int it = 0; it < 16; ++it) {
        int flat = (it * 512 + tid) * 8;
        int r = flat >> 7, chunk = (flat >> 3) & 15;
        *(half8*)(whh1 + r * 128 + ((chunk ^ (r & 15)) * 8)) = *(const half8*)(whh1g + flat);
    }
    {
        half8 z;
        #pragma unroll
        for (int jj = 0; jj < 8; ++jj) z[jj] = (_Float16)0.0f;
        for (int i = tid * 8; i < 8192; i += 4096) *(half8*)(h0b + i) = z;
    }
    if (tid < 128) woutl[tid] = (_Float16)w_out[tid];

    half8 whh0f[4][4], wih1f[4][4];
    float bias0[4], bias1[4];
    #pragma unroll
    for (int nt = 0; nt < 4; ++nt) {
        int j = nt * 128 + j0;
        float sc = (nt == 2) ? LOG2E2 : LOG2E;
        #pragma unroll
        for (int kt = 0; kt < 4; ++kt) {
            whh0f[nt][kt] = *(const half8*)(wsw + WH_HH0 + j * 128 + kt * 32 + quad * 8);
            wih1f[nt][kt] = *(const half8*)(wsw + WH_IH1 + j * 128 + kt * 32 + quad * 8);
        }
        bias0[nt] = (b_ih0[j] + b_hh0[j]) * sc;
        bias1[nt] = (b_ih1[j] + b_hh1[j]) * sc;
    }
    const float bout = b_out[0];

    int swz[4], hoff[4], w0off[4];
    #pragma unroll
    for (int kt = 0; kt < 4; ++kt) {
        swz[kt]  = ((kt * 4 + quad) ^ col) * 8;
        hoff[kt] = col * 128 + swz[kt];
    }
    #pragma unroll
    for (int i = 0; i < 4; ++i) {
        int row = quad * 4 + i;
        w0off[i] = row * 128 + (((2 * w + (col >> 3)) ^ row) * 8) + (col & 7);
    }
    float c0[4] = {0.f,0.f,0.f,0.f}, c1[4] = {0.f,0.f,0.f,0.f};

    const _Float16* xph = wsw + WH_X2 + (size_t)(rowbase + col) * DIN + quad * 8;
    const float*    xpf = state32 + (size_t)(rowbase + col) * DIN + quad * 8;
    half8 nxh0, nxh1;
    f32x4 nxf0, nxf1, nxf2, nxf3;
    if constexpr (XH) {
        nxh0 = *(const half8*)(xph); nxh1 = *(const half8*)(xph + 32);
    } else {
        nxf0 = *(const f32x4*)(xpf);      nxf1 = *(const f32x4*)(xpf + 4);
        nxf2 = *(const f32x4*)(xpf + 32); nxf3 = *(const f32x4*)(xpf + 36);
    }
    __syncthreads();
    const _Float16* wih0g = wsw + WH_IH0;

    #pragma unroll 1
    for (int t = 0; t < T_STEPS; ++t) {
        const int pbo = (t & 1) * 2048, cbo = pbo ^ 2048;
        half8 ax0, ax1;
        if constexpr (XH) { ax0 = nxh0; ax1 = nxh1; }
        else {
            #pragma unroll
            for (int jj = 0; jj < 4; ++jj) {
                ax0[jj]   = (_Float16)nxf0[jj]; ax0[jj+4] = (_Float16)nxf1[jj];
                ax1[jj]   = (_Float16)nxf2[jj]; ax1[jj+4] = (_Float16)nxf3[jj];
            }
        }
        half8 wif[4][2];
        #pragma unroll
        for (int nt = 0; nt < 4; ++nt)
            #pragma unroll
            for (int kt = 0; kt < 2; ++kt)
                wif[nt][kt] = *(const half8*)(wih0g + (nt * 128 + j0) * 64 + kt * 32 + quad * 8);
        half8 ah[4];
        #pragma unroll
        for (int kt = 0; kt < 4; ++kt)
            ah[kt] = *(const half8*)(h0b + pbo + hoff[kt]);

        f32x4 acc[4];
        #pragma unroll
        for (int nt = 0; nt < 4; ++nt) {
            f32x4 b = {bias0[nt], bias0[nt], bias0[nt], bias0[nt]};
            acc[nt] = b;
        }
        #pragma unroll
        for (int kt = 0; kt < 4; ++kt)
            #pragma unroll
            for (int nt = 0; nt < 4; ++nt)
                acc[nt] = __builtin_amdgcn_mfma_f32_16x16x32_f16(ah[kt], whh0f[nt][kt], acc[nt], 0, 0, 0);
        #pragma unroll
        for (int kt = 0; kt < 2; ++kt) {
            half8 axk = kt ? ax1 : ax0;
            #pragma unroll
            for (int nt = 0; nt < 4; ++nt)
                acc[nt] = __builtin_amdgcn_mfma_f32_16x16x32_f16(axk, wif[nt][kt], acc[nt], 0, 0, 0);
        }
        {
            int tn = (t + 1 < T_STEPS) ? t + 1 : t;
            if constexpr (XH) {
                const _Float16* xq = xph + (size_t)tn * (BATCH * DIN);
                nxh0 = *(const half8*)(xq); nxh1 = *(const half8*)(xq + 32);
            } else {
                const float* xq = xpf + (size_t)tn * (BATCH * DIN);
                nxf0 = *(const f32x4*)(xq);      nxf1 = *(const f32x4*)(xq + 4);
                nxf2 = *(const f32x4*)(xq + 32); nxf3 = *(const f32x4*)(xq + 36);
            }
        }
        #pragma unroll
        for (int i = 0; i < 4; ++i) {
            float ig = sig2(acc[0][i]);
            float fg = sig2(acc[1][i]);
            float gg = tanh2(acc[2][i]);
            float og = sig2(acc[3][i]);
            float c  = fg * c0[i] + ig * gg;
            c0[i] = c;
            h0b[cbo + w0off[i]] = (_Float16)(og * tanh_c(c));
        }
        __syncthreads();

        #pragma unroll
        for (int nt = 0; nt < 4; ++nt) {
            f32x4 b = {bias1[nt], bias1[nt], bias1[nt], bias1[nt]};
            acc[nt] = b;
        }
        #pragma unroll
        for (int kt = 0; kt < 4; ++kt) {
            half8 a0 = *(const half8*)(h0b + cbo + hoff[kt]);
            half8 a1 = *(const half8*)(h1b + pbo + hoff[kt]);
            #pragma unroll
            for (int nt = 0; nt < 4; ++nt)
                acc[nt] = __builtin_amdgcn_mfma_f32_16x16x32_f16(a0, wih1f[nt][kt], acc[nt], 0, 0, 0);
            #pragma unroll
            for (int nt = 0; nt < 4; ++nt) {
                half8 bfr = *(const half8*)(whh1 + nt * 16384 + j0 * 128 + swz[kt]);
                acc[nt] = __builtin_amdgcn_mfma_f32_16x16x32_f16(a1, bfr, acc[nt], 0, 0, 0);
            }
        }
        #pragma unroll
        for (int i = 0; i < 4; ++i) {
            float ig = sig2(acc[0][i]);
            float fg = sig2(acc[1][i]);
            float gg = tanh2(acc[2][i]);
            float og = sig2(acc[3][i]);
            float c  = fg * c1[i] + ig * gg;
            c1[i] = c;
            h1b[cbo + w0off[i]] = (_Float16)(og * tanh_c(c));
        }
        if (w == 7) {
            f32x4 vh = {0.f, 0.f, 0.f, 0.f};
            #pragma unroll
            for (int kt = 0; kt < 4; ++kt) {
                half8 a1 = *(const half8*)(h1b + pbo + hoff[kt]);
                half8 bw = *(const half8*)(woutl + kt * 32 + quad * 8);
                if (col != 0) {
                    #pragma unroll
                    for (int jj = 0; jj < 8; ++jj) bw[jj] = (_Float16)0.0f;
                }
                vh = __builtin_amdgcn_mfma_f32_16x16x32_f16(a1, bw, vh, 0, 0, 0);
            }
            if (t > 0 && col == 0) {
                f32x4 vo = {vh[0] + bout, vh[1] + bout, vh[2] + bout, vh[3] + bout};
                *(f32x4*)(out + (size_t)(t - 1) * BATCH + rowbase + quad * 4) = vo;
            }
        }
    }
    __syncthreads();
    if (w == 7) {
        const int fbo = (((T_STEPS - 1) & 1) ^ 1) * 2048;
        f32x4 vh = {0.f, 0.f, 0.f, 0.f};
        #pragma unroll
        for (int kt = 0; kt < 4; ++kt) {
            half8 a1 = *(const half8*)(h1b + fbo + hoff[kt]);
            half8 bw = *(const half8*)(woutl + kt * 32 + quad * 8);
            if (col != 0) {
                #pragma unroll
                for (int jj = 0; jj < 8; ++jj) bw[jj] = (_Float16)0.0f;
            }
            vh = __builtin_amdgcn_mfma_f32_16x16x32_f16(a1, bw, vh, 0, 0, 0);
        }
        if (col == 0) {
            f32x4 vo = {vh[0] + bout, vh[1] + bout, vh[2] + bout, vh[3] + bout};
            *(f32x4*)(out + (size_t)(T_STEPS - 1) * BATCH + rowbase + quad * 4) = vo;
        }
    }
}

extern "C" void kernel_launch(void* const* d_in, const int* in_sizes, int n_in,
                              void* d_out, int out_size, void* d_ws, size_t ws_size,
                              hipStream_t stream) {
    const float* state = (const float*)d_in[0];
    const float* wih0  = (const float*)d_in[1];
    const float* whh0  = (const float*)d_in[2];
    const float* bih0  = (const float*)d_in[3];
    const float* bhh0  = (const float*)d_in[4];
    const float* wih1  = (const float*)d_in[5];
    const float* whh1  = (const float*)d_in[6];
    const float* bih1  = (const float*)d_in[7];
    const float* bhh1  = (const float*)d_in[8];
    const float* wout  = (const float*)d_in[9];
    const float* bout  = (const float*)d_in[10];
    _Float16* wsh = (_Float16*)d_ws;
    float* outp = (float*)d_out;

    prep_weights<<<896, 256, 0, stream>>>(wih0, whh0, wih1, whh1, wsh);

    if (ws_size >= WS2_TOTAL) {
        prep_state<<<4096, 256, 0, stream>>>(state, wsh + WH_X2);
        lstm_pipe<true><<<32, 512, PIPE_LDS_BYTES, stream>>>(
            state, wsh, bih0, bhh0, bih1, bhh1, wout, bout,
            wsh + WH_SLAB2, (int*)((char*)d_ws + WB_FLAG2), wsh + WH_X2, outp);
    } else if (ws_size >= WS1_TOTAL) {
        lstm_pipe<false><<<32, 512, PIPE_LDS_BYTES, stream>>>(
            state, wsh, bih0, bhh0, bih1, bhh1, wout, bout,
            wsh + WH_SLAB1, (int*)((char*)d_ws + WB_FLAG1), nullptr, outp);
    } else if (ws_size >= WS0XH_TOTAL) {
        prep_state<<<4096, 256, 0, stream>>>(state, wsh + WH_X2);
        lstm_mono<true><<<16, 512, MONO_LDS_BYTES, stream>>>(
            state, wsh, bih0, bhh0, bih1, bhh1, wout, bout, outp);
    } else {
        lstm_mono<false><<<16, 512, MONO_LDS_BYTES, stream>>>(
            state, wsh, bih0, bhh0, bih1, bhh1, wout, bout, outp);
    }
}